// Round 1
// baseline (111.252 us; speedup 1.0000x reference)
//
#include <hip/hip_runtime.h>
#include <hip/hip_bf16.h>
#include <cstdint>

typedef float f32x4 __attribute__((ext_vector_type(4)));
typedef short bf16x8 __attribute__((ext_vector_type(8)));

#define BATCH 32
#define CIN   128
#define HIMG  56
#define WIMG  56
#define HWSZ  3136      // 56*56
#define OCH   256
#define HP    58
#define WP    58

#define BM 128
#define BN 128
#define BK 64
#define NSTEP 18        // 9 (i,j) positions x 2 c-chunks of 64

// ---- prep 1: x [B][C][H][W] f32 -> xb padded NHWC bf16 [B][58][58][128] ----
__global__ void cast_transpose_x(const float* __restrict__ x,
                                 __hip_bfloat16* __restrict__ xb) {
    __shared__ float tile[32][33];
    const int hw0 = blockIdx.x * 32;
    const int c0  = blockIdx.y * 32;
    const int b   = blockIdx.z;
    const int tx  = threadIdx.x;   // 0..31
    const int ty  = threadIdx.y;   // 0..7

    const float* src = x + ((size_t)(b * CIN + c0) * HWSZ) + hw0;
#pragma unroll
    for (int k = 0; k < 4; ++k) {
        int c = ty + k * 8;
        tile[c][tx] = src[(size_t)c * HWSZ + tx];
    }
    __syncthreads();
#pragma unroll
    for (int k = 0; k < 4; ++k) {
        int hwl = ty + k * 8;
        int hw = hw0 + hwl;
        int h = hw / WIMG;
        int w = hw - h * WIMG;
        size_t dst = (((size_t)b * HP + (h + 1)) * WP + (w + 1)) * CIN + c0 + tx;
        xb[dst] = __float2bfloat16(tile[tx][hwl]);
    }
}

// ---- prep 2: weight [O][C][3][3] f32 -> wb bf16 [ij][O][C] ----
__global__ void prep_w(const float* __restrict__ wsrc,
                       __hip_bfloat16* __restrict__ wb) {
    int idx = blockIdx.x * 256 + threadIdx.x;   // < 9*256*128
    int c    = idx & 127;
    int rest = idx >> 7;
    int o    = rest & 255;
    int ij   = rest >> 8;   // 0..8
    wb[idx] = __float2bfloat16(wsrc[((size_t)o * CIN + c) * 9 + ij]);
}

// ---- async global->LDS 16B helper ----
__device__ __forceinline__ void gload16(const void* g, void* l) {
    __builtin_amdgcn_global_load_lds(
        (const __attribute__((address_space(1))) unsigned*)g,
        (__attribute__((address_space(3))) unsigned*)l,
        16, 0, 0);
}

// ---- main implicit-GEMM conv kernel ----
// A: pixels (M) x K, staged [128 rows][64 k] bf16 per step (source pre-XOR-swizzled)
// B: weights K x O, staged as [128 n][64 k] bf16 (k-major rows)
__global__ __launch_bounds__(256, 2)
void conv_gemm(const __hip_bfloat16* __restrict__ xb,
               const __hip_bfloat16* __restrict__ wb,
               const float* __restrict__ bias,
               float* __restrict__ out) {
    __shared__ __attribute__((aligned(16))) char smem[65536]; // 2 bufs x (A 16K + B 16K)

    const int tid = threadIdx.x;
    const int wv  = tid >> 6;
    const int ln  = tid & 63;

    const int bid = blockIdx.x;
    const int mt  = bid >> 1;
    const int nt  = bid & 1;
    const int m0  = mt * BM;
    const int n0  = nt * BN;

    // ---- staging precompute ----
    const int rl = ln >> 3;        // row-in-chunk 0..7 (== row&7 for all q)
    const int cs = ln & 7;         // 16B col slot
    const int colsrc = ((cs * 16) ^ (rl << 4)) >> 1;  // pre-swizzled source col (elems)

    const __hip_bfloat16* aSrc[4];
    const __hip_bfloat16* bSrc[4];
#pragma unroll
    for (int q = 0; q < 4; ++q) {
        int row = wv * 32 + q * 8 + rl;
        int p  = m0 + row;
        int b  = p / HWSZ;
        int hw = p - b * HWSZ;
        int h  = hw / WIMG;
        int w  = hw - h * WIMG;
        // padded coords: input pixel for (i,j) is (h+i, w+j) in [0..57]
        aSrc[q] = xb + (((size_t)b * HP + h) * WP + w) * CIN + colsrc;
        int n = n0 + row;
        bSrc[q] = wb + (size_t)n * CIN + colsrc;
    }
    const int ldst = wv * 4096 + ln * 16;   // byte offset within a 16K tile

#define STAGE(buf, s) do {                                             \
        int ij_  = (s) >> 1;                                           \
        int ck0_ = ((s) & 1) << 6;                                     \
        int ii_  = ij_ / 3;                                            \
        int jj_  = ij_ - ii_ * 3;                                      \
        int offA_ = (ii_ * WP + jj_) * CIN + ck0_;                     \
        int offB_ = ij_ * (OCH * CIN) + ck0_;                          \
        char* bA_ = smem + (buf) * 32768;                              \
        char* bB_ = bA_ + 16384;                                       \
        _Pragma("unroll")                                              \
        for (int q_ = 0; q_ < 4; ++q_) {                               \
            gload16(aSrc[q_] + offA_, bA_ + ldst + q_ * 1024);         \
            gload16(bSrc[q_] + offB_, bB_ + ldst + q_ * 1024);         \
        }                                                              \
    } while (0)

    // ---- compute-side constants ----
    const int wm = wv >> 1, wn = wv & 1;
    const int laneM = ln & 15;
    const int laneK = ln >> 4;
    const int swz   = (laneM & 7) << 4;
    const int arow0 = (wm * 64 + laneM) * 128;   // byte offset of row base
    const int brow0 = (wn * 64 + laneM) * 128;

    f32x4 acc[4][4] = {};

    int cur = 0;
    STAGE(0, 0);

#pragma unroll 2
    for (int s = 0; s < NSTEP; ++s) {
        __syncthreads();                 // compiler drains vmcnt before barrier
        if (s + 1 < NSTEP) STAGE(cur ^ 1, s + 1);
        const char* baseA = smem + cur * 32768;
        const char* baseB = baseA + 16384;
#pragma unroll
        for (int kk = 0; kk < 2; ++kk) {
            const int kb  = kk * 64 + laneK * 16;
            const int kbs = kb ^ swz;
            bf16x8 af[4], bfr[4];
#pragma unroll
            for (int mi = 0; mi < 4; ++mi)
                af[mi] = *(const bf16x8*)(baseA + arow0 + mi * (16 * 128) + kbs);
#pragma unroll
            for (int ni = 0; ni < 4; ++ni)
                bfr[ni] = *(const bf16x8*)(baseB + brow0 + ni * (16 * 128) + kbs);
#pragma unroll
            for (int mi = 0; mi < 4; ++mi)
#pragma unroll
                for (int ni = 0; ni < 4; ++ni)
                    acc[mi][ni] = __builtin_amdgcn_mfma_f32_16x16x32_bf16(
                        af[mi], bfr[ni], acc[mi][ni], 0, 0, 0);
        }
        cur ^= 1;
    }
#undef STAGE

    // ---- epilogue: C/D mapping col=lane&15 (n), row=(lane>>4)*4+reg (pixel) ----
    const int laneC = ln & 15;
    const int laneR = (ln >> 4) * 4;
    float bn[4];
#pragma unroll
    for (int ni = 0; ni < 4; ++ni)
        bn[ni] = bias[n0 + wn * 64 + ni * 16 + laneC];

#pragma unroll
    for (int mi = 0; mi < 4; ++mi) {
        int p0 = m0 + wm * 64 + mi * 16 + laneR;   // multiple of 4; HWSZ%4==0
        int b  = p0 / HWSZ;
        int hw = p0 - b * HWSZ;
#pragma unroll
        for (int ni = 0; ni < 4; ++ni) {
            int n = n0 + wn * 64 + ni * 16 + laneC;
            float4 v;
            v.x = acc[mi][ni][0] + bn[ni];
            v.y = acc[mi][ni][1] + bn[ni];
            v.z = acc[mi][ni][2] + bn[ni];
            v.w = acc[mi][ni][3] + bn[ni];
            *(float4*)(out + ((size_t)(b * OCH + n) * HWSZ + hw)) = v;
        }
    }
}

extern "C" void kernel_launch(void* const* d_in, const int* in_sizes, int n_in,
                              void* d_out, int out_size, void* d_ws, size_t ws_size,
                              hipStream_t stream) {
    const float* x    = (const float*)d_in[0];
    const float* w    = (const float*)d_in[1];
    const float* bias = (const float*)d_in[2];
    float* out = (float*)d_out;

    char* ws = (char*)d_ws;
    __hip_bfloat16* xbuf = (__hip_bfloat16*)ws;                   // 32*58*58*128*2 = 27,557,888 B
    __hip_bfloat16* wbuf = (__hip_bfloat16*)(ws + 27557888);      // 9*256*128*2   =    589,824 B

    hipMemsetAsync(xbuf, 0, 27557888, stream);                    // zero padded border
    cast_transpose_x<<<dim3(98, 4, 32), dim3(32, 8), 0, stream>>>(x, xbuf);
    prep_w<<<9 * 256 * 128 / 256, 256, 0, stream>>>(w, wbuf);
    conv_gemm<<<(100352 / BM) * (OCH / BN), 256, 0, stream>>>(xbuf, wbuf, bias, out);
}

// Round 2
// 105.085 us; speedup vs baseline: 1.0587x; 1.0587x over previous
//
#include <hip/hip_runtime.h>
#include <hip/hip_bf16.h>
#include <cstdint>

typedef float f32x4 __attribute__((ext_vector_type(4)));
typedef short bf16x8 __attribute__((ext_vector_type(8)));

#define CIN   128
#define WIMG  56
#define HWSZ  3136      // 56*56
#define OCH   256
#define HP    58
#define WP    58
#define NT    18        // 9 (i,j) taps x 2 c-chunks of 64

// ---- prep 0: zero only the padded border of xb (1.9 MB, not 27.5 MB memset) ----
__global__ void zero_border(__hip_bfloat16* __restrict__ xb) {
    int idx = blockIdx.x * 256 + threadIdx.x;   // 32*228*16 = 116736 total
    int c8  = idx & 15;
    int t   = idx >> 4;
    int b   = t / 228;
    int pos = t - b * 228;
    int h, w;
    if (pos < 58)       { h = 0;             w = pos; }
    else if (pos < 116) { h = 57;            w = pos - 58; }
    else if (pos < 172) { h = pos - 116 + 1; w = 0; }
    else                { h = pos - 172 + 1; w = 57; }
    uint4 z = {0, 0, 0, 0};
    *(uint4*)((char*)xb + (((size_t)(b * HP + h) * WP + w) * CIN + c8 * 8) * 2) = z;
}

// ---- prep 1: x [B][C][H][W] f32 -> xb padded NHWC bf16 [B][58][58][128] ----
__global__ void cast_transpose_x(const float* __restrict__ x,
                                 __hip_bfloat16* __restrict__ xb) {
    __shared__ float tile[32][33];
    const int hw0 = blockIdx.x * 32;
    const int c0  = blockIdx.y * 32;
    const int b   = blockIdx.z;
    const int tx  = threadIdx.x;   // 0..31
    const int ty  = threadIdx.y;   // 0..7

    const float* src = x + ((size_t)(b * CIN + c0) * HWSZ) + hw0;
#pragma unroll
    for (int k = 0; k < 4; ++k) {
        int c = ty + k * 8;
        tile[c][tx] = src[(size_t)c * HWSZ + tx];
    }
    __syncthreads();
#pragma unroll
    for (int k = 0; k < 4; ++k) {
        int hwl = ty + k * 8;
        int hw = hw0 + hwl;
        int h = hw / WIMG;
        int w = hw - h * WIMG;
        size_t dst = (((size_t)b * HP + (h + 1)) * WP + (w + 1)) * CIN + c0 + tx;
        xb[dst] = __float2bfloat16(tile[tx][hwl]);
    }
}

// ---- prep 2: weight [O][C][3][3] f32 -> wb bf16 [ij][O][C] ----
__global__ void prep_w(const float* __restrict__ wsrc,
                       __hip_bfloat16* __restrict__ wb) {
    int idx = blockIdx.x * 256 + threadIdx.x;   // < 9*256*128
    int c    = idx & 127;
    int rest = idx >> 7;
    int o    = rest & 255;
    int ij   = rest >> 8;   // 0..8
    wb[idx] = __float2bfloat16(wsrc[((size_t)o * CIN + c) * 9 + ij]);
}

// ---- async global->LDS 16B ----
__device__ __forceinline__ void gload16(const void* g, void* l) {
    __builtin_amdgcn_global_load_lds(
        (const __attribute__((address_space(1))) unsigned*)g,
        (__attribute__((address_space(3))) unsigned*)l,
        16, 0, 0);
}

// ---- main implicit-GEMM conv: 256x256 tile, BK=64, 8 waves (2Mx4N), 4-phase ----
__global__ __launch_bounds__(512, 2)
void conv_gemm(const __hip_bfloat16* __restrict__ xb,
               const __hip_bfloat16* __restrict__ wb,
               const float* __restrict__ bias,
               float* __restrict__ out) {
    extern __shared__ __attribute__((aligned(16))) char smem[];  // 131072: 2 x [A 32K | B 32K]

    const int tid = threadIdx.x;
    const int wv  = tid >> 6;
    const int ln  = tid & 63;

    int bid = blockIdx.x;
    bid = (bid & 7) * 49 + (bid >> 3);        // XCD swizzle: 392 = 8*49, bijective
    const int m0 = bid * 256;

    // ---- staging addresses (pre-swizzled source, linear LDS dest) ----
    const int srow = tid >> 3;                // 0..63
    const int cs   = tid & 7;                 // 16B slot
    const int colsrc = ((cs * 16) ^ ((srow & 7) << 4)) >> 1;   // elems within 64-k chunk
    int aOff[4], bOff[4];
#pragma unroll
    for (int q = 0; q < 4; ++q) {
        int row = q * 64 + srow;
        int p  = m0 + row;
        int b  = p / HWSZ;
        int hw = p - b * HWSZ;
        int h  = hw / WIMG;
        int w  = hw - h * WIMG;
        aOff[q] = ((b * HP + h) * WP + w) * CIN + colsrc;
        bOff[q] = row * CIN + colsrc;
    }
    const int ldsd = tid * 16;

#define SA(buf,q,offA_) gload16(xb + aOff[q] + (offA_), smem + (buf)*65536 + (q)*8192 + ldsd)
#define SB(buf,q,offB_) gload16(wb + bOff[q] + (offB_), smem + (buf)*65536 + 32768 + (q)*8192 + ldsd)

    // ---- compute-side constants ----
    const int wm  = wv >> 2;                  // 0..1 : rows [wm*128, +128)
    const int wn  = wv & 3;                   // 0..3 : cols [wn*64, +64)
    const int fr  = ln & 15;
    const int kby = (ln >> 4) * 16;
    const int swz = (ln & 7) << 4;

    f32x4 acc[8][4] = {};
    bf16x8 af[4][2], bq0[2][2], bq1[2][2];

#define READ_A(base, mh) do {                                                 \
    _Pragma("unroll") for (int mi = 0; mi < 4; ++mi)                          \
    _Pragma("unroll") for (int kk = 0; kk < 2; ++kk)                          \
        af[mi][kk] = *(const bf16x8*)((base) +                                \
            (wm*128 + (mh)*64 + mi*16 + fr)*128 + ((kk*64 + kby) ^ swz));     \
} while (0)

#define READ_B(base, nh, dst) do {                                            \
    _Pragma("unroll") for (int ni = 0; ni < 2; ++ni)                          \
    _Pragma("unroll") for (int kk = 0; kk < 2; ++kk)                          \
        dst[ni][kk] = *(const bf16x8*)((base) + 32768 +                       \
            (wn*64 + (nh)*32 + ni*16 + fr)*128 + ((kk*64 + kby) ^ swz));      \
} while (0)

#define MQ(mh, nh, B) do {                                                    \
    _Pragma("unroll") for (int kk = 0; kk < 2; ++kk)                          \
    _Pragma("unroll") for (int mi = 0; mi < 4; ++mi)                          \
    _Pragma("unroll") for (int ni = 0; ni < 2; ++ni)                          \
        acc[(mh)*4+mi][(nh)*2+ni] = __builtin_amdgcn_mfma_f32_16x16x32_bf16(  \
            af[mi][kk], B[ni][kk], acc[(mh)*4+mi][(nh)*2+ni], 0, 0, 0);       \
} while (0)

    // ---- prologue: stage K-tile 0 into buf 0 ----
    SA(0,0,0); SA(0,1,0); SA(0,2,0); SA(0,3,0);
    SB(0,0,0); SB(0,1,0); SB(0,2,0); SB(0,3,0);
    asm volatile("s_waitcnt vmcnt(0)" ::: "memory");
    __builtin_amdgcn_s_barrier();

#pragma unroll 2
    for (int t = 0; t < NT; ++t) {
        const int cur = t & 1;
        const char* base = smem + cur * 65536;
        const int  nx = cur ^ 1;
        const bool pf = (t + 1 < NT);
        const int s   = t + 1;
        const int ij  = s >> 1;
        const int ck0 = (s & 1) << 6;
        const int ii  = ij / 3;
        const int jj  = ij - ii * 3;
        const int offA = (ii * WP + jj) * CIN + ck0;
        const int offB = ij * (OCH * CIN) + ck0;

        // phase 0: quad (0,0) — read A-half0 + B-half0, stage 3
        if (pf) { SA(nx,0,offA); SA(nx,1,offA); SA(nx,2,offA); }
        READ_A(base, 0);
        READ_B(base, 0, bq0);
        __builtin_amdgcn_s_barrier();
        asm volatile("s_waitcnt lgkmcnt(0)" ::: "memory");
        __builtin_amdgcn_s_setprio(1);
        MQ(0, 0, bq0);
        __builtin_amdgcn_s_setprio(0);
        __builtin_amdgcn_s_barrier();

        // phase 1: quad (0,1) — read B-half1, reuse A-half0, stage 3
        if (pf) { SA(nx,3,offA); SB(nx,0,offB); SB(nx,1,offB); }
        READ_B(base, 1, bq1);
        __builtin_amdgcn_s_barrier();
        asm volatile("s_waitcnt lgkmcnt(0)" ::: "memory");
        __builtin_amdgcn_s_setprio(1);
        MQ(0, 1, bq1);
        __builtin_amdgcn_s_setprio(0);
        __builtin_amdgcn_s_barrier();

        // phase 2: quad (1,1) — read A-half1, reuse B-half1, stage 2
        if (pf) { SB(nx,2,offB); SB(nx,3,offB); }
        READ_A(base, 1);
        __builtin_amdgcn_s_barrier();
        asm volatile("s_waitcnt lgkmcnt(0)" ::: "memory");
        __builtin_amdgcn_s_setprio(1);
        MQ(1, 1, bq1);
        __builtin_amdgcn_s_setprio(0);
        __builtin_amdgcn_s_barrier();

        // phase 3: quad (1,0) — no reads (reuse A-half1 + B-half0); boundary
        __builtin_amdgcn_s_setprio(1);
        MQ(1, 0, bq0);
        __builtin_amdgcn_s_setprio(0);
        asm volatile("s_waitcnt vmcnt(0)" ::: "memory");   // t+1's 8 loads landed
        __builtin_amdgcn_s_barrier();
        __builtin_amdgcn_sched_barrier(0);
    }
#undef SA
#undef SB
#undef READ_A
#undef READ_B
#undef MQ

    // ---- epilogue: C/D map col=ln&15 (n), row=(ln>>4)*4+reg (pixel) ----
    const int laneR4 = (ln >> 4) * 4;
    float bn[4];
#pragma unroll
    for (int ni = 0; ni < 4; ++ni)
        bn[ni] = bias[wn * 64 + ni * 16 + fr];

#pragma unroll
    for (int mi = 0; mi < 8; ++mi) {
        int p0 = m0 + wm * 128 + mi * 16 + laneR4;   // multiple of 4, HWSZ%4==0
        int b  = p0 / HWSZ;
        int hw = p0 - b * HWSZ;
#pragma unroll
        for (int ni = 0; ni < 4; ++ni) {
            int n = wn * 64 + ni * 16 + fr;
            float4 v;
            v.x = acc[mi][ni][0] + bn[ni];
            v.y = acc[mi][ni][1] + bn[ni];
            v.z = acc[mi][ni][2] + bn[ni];
            v.w = acc[mi][ni][3] + bn[ni];
            *(float4*)(out + ((size_t)(b * OCH + n) * HWSZ + hw)) = v;
        }
    }
}

extern "C" void kernel_launch(void* const* d_in, const int* in_sizes, int n_in,
                              void* d_out, int out_size, void* d_ws, size_t ws_size,
                              hipStream_t stream) {
    const float* x    = (const float*)d_in[0];
    const float* w    = (const float*)d_in[1];
    const float* bias = (const float*)d_in[2];
    float* out = (float*)d_out;

    char* ws = (char*)d_ws;
    __hip_bfloat16* xbuf = (__hip_bfloat16*)ws;                   // 32*58*58*128*2 = 27,557,888 B
    __hip_bfloat16* wbuf = (__hip_bfloat16*)(ws + 27557888);      // 9*256*128*2   =    589,824 B

    hipFuncSetAttribute(reinterpret_cast<const void*>(conv_gemm),
                        hipFuncAttributeMaxDynamicSharedMemorySize, 131072);

    zero_border<<<456, 256, 0, stream>>>(xbuf);
    cast_transpose_x<<<dim3(98, 4, 32), dim3(32, 8), 0, stream>>>(x, xbuf);
    prep_w<<<9 * 256 * 128 / 256, 256, 0, stream>>>(w, wbuf);
    conv_gemm<<<392, 512, 131072, stream>>>(xbuf, wbuf, bias, out);
}

// Round 3
// 104.138 us; speedup vs baseline: 1.0683x; 1.0091x over previous
//
#include <hip/hip_runtime.h>
#include <hip/hip_bf16.h>
#include <cstdint>

typedef float f32x4 __attribute__((ext_vector_type(4)));
typedef short bf16x8 __attribute__((ext_vector_type(8)));

#define CIN   128
#define WIMG  56
#define HWSZ  3136      // 56*56
#define OCH   256
#define HP    58
#define WP    58
#define NT    18        // 9 (i,j) taps x 2 c-chunks of 64

// ---- prep 0: zero only the padded border of xb ----
__global__ void zero_border(__hip_bfloat16* __restrict__ xb) {
    int idx = blockIdx.x * 256 + threadIdx.x;   // 32*228*16 = 116736 total
    int c8  = idx & 15;
    int t   = idx >> 4;
    int b   = t / 228;
    int pos = t - b * 228;
    int h, w;
    if (pos < 58)       { h = 0;             w = pos; }
    else if (pos < 116) { h = 57;            w = pos - 58; }
    else if (pos < 172) { h = pos - 116 + 1; w = 0; }
    else                { h = pos - 172 + 1; w = 57; }
    uint4 z = {0, 0, 0, 0};
    *(uint4*)((char*)xb + (((size_t)(b * HP + h) * WP + w) * CIN + c8 * 8) * 2) = z;
}

// ---- prep 1: x [B][C][H][W] f32 -> xb padded NHWC bf16 [B][58][58][128] ----
__global__ void cast_transpose_x(const float* __restrict__ x,
                                 __hip_bfloat16* __restrict__ xb) {
    __shared__ float tile[32][33];
    const int hw0 = blockIdx.x * 32;
    const int c0  = blockIdx.y * 32;
    const int b   = blockIdx.z;
    const int tx  = threadIdx.x;
    const int ty  = threadIdx.y;

    const float* src = x + ((size_t)(b * CIN + c0) * HWSZ) + hw0;
#pragma unroll
    for (int k = 0; k < 4; ++k) {
        int c = ty + k * 8;
        tile[c][tx] = src[(size_t)c * HWSZ + tx];
    }
    __syncthreads();
#pragma unroll
    for (int k = 0; k < 4; ++k) {
        int hwl = ty + k * 8;
        int hw = hw0 + hwl;
        int h = hw / WIMG;
        int w = hw - h * WIMG;
        size_t dst = (((size_t)b * HP + (h + 1)) * WP + (w + 1)) * CIN + c0 + tx;
        xb[dst] = __float2bfloat16(tile[tx][hwl]);
    }
}

// ---- prep 2: weight [O][C][3][3] f32 -> wb bf16 [ij][O][C] ----
__global__ void prep_w(const float* __restrict__ wsrc,
                       __hip_bfloat16* __restrict__ wb) {
    int idx = blockIdx.x * 256 + threadIdx.x;
    int c    = idx & 127;
    int rest = idx >> 7;
    int o    = rest & 255;
    int ij   = rest >> 8;
    wb[idx] = __float2bfloat16(wsrc[((size_t)o * CIN + c) * 9 + ij]);
}

// ---- async global->LDS 16B ----
__device__ __forceinline__ void gload16(const void* g, void* l) {
    __builtin_amdgcn_global_load_lds(
        (const __attribute__((address_space(1))) unsigned*)g,
        (__attribute__((address_space(3))) unsigned*)l,
        16, 0, 0);
}

// ---- main: 256x256 tile, BK=64, 8 waves (2Mx4N), m201-style 8-phase, 2 K-tiles/iter ----
__global__ __launch_bounds__(512, 2)
void conv_gemm(const __hip_bfloat16* __restrict__ xb,
               const __hip_bfloat16* __restrict__ wb,
               const float* __restrict__ bias,
               float* __restrict__ out) {
    extern __shared__ __attribute__((aligned(16))) char smem[];  // 131072: buf0 [A32K|B32K] buf1 [A32K|B32K]

    const int tid = threadIdx.x;
    const int wv  = tid >> 6;
    const int ln  = tid & 63;

    int bid = blockIdx.x;
    bid = (bid & 7) * 49 + (bid >> 3);        // XCD swizzle: 392 = 8*49, bijective
    const int m0 = bid * 256;

    // ---- staging addresses (pre-swizzled source, linear LDS dest) ----
    const int srow = tid >> 3;                // 0..63
    const int cs   = tid & 7;                 // 16B slot
    const int colsrc = ((cs * 16) ^ ((srow & 7) << 4)) >> 1;
    int aOff[4], bOff[4];
#pragma unroll
    for (int q = 0; q < 4; ++q) {
        int row = q * 64 + srow;
        int p  = m0 + row;
        int b  = p / HWSZ;
        int hw = p - b * HWSZ;
        int h  = hw / WIMG;
        int w  = hw - h * WIMG;
        aOff[q] = ((b * HP + h) * WP + w) * CIN + colsrc;
        bOff[q] = row * CIN + colsrc;
    }
    const int ldsd = tid * 16;

#define SA(buf,q,offA_) gload16(xb + aOff[q] + (offA_), smem + (buf)*65536 + (q)*8192 + ldsd)
#define SB(buf,q,offB_) gload16(wb + bOff[q] + (offB_), smem + (buf)*65536 + 32768 + (q)*8192 + ldsd)

    // ---- compute-side constants ----
    const int wm  = wv >> 2;                  // rows [wm*128, +128)
    const int wn  = wv & 3;                   // cols [wn*64, +64)
    const int fr  = ln & 15;
    const int kby = (ln >> 4) * 16;
    const int swz = (ln & 7) << 4;

    f32x4 acc[8][4] = {};
    bf16x8 af[4][2], bq0[2][2], bq1[2][2];

#define READ_A(base, mh) do {                                                 \
    _Pragma("unroll") for (int mi = 0; mi < 4; ++mi)                          \
    _Pragma("unroll") for (int kk = 0; kk < 2; ++kk)                          \
        af[mi][kk] = *(const bf16x8*)((base) +                                \
            (wm*128 + (mh)*64 + mi*16 + fr)*128 + ((kk*64 + kby) ^ swz));     \
} while (0)

#define READ_B(base, nh, dst) do {                                            \
    _Pragma("unroll") for (int ni = 0; ni < 2; ++ni)                          \
    _Pragma("unroll") for (int kk = 0; kk < 2; ++kk)                          \
        dst[ni][kk] = *(const bf16x8*)((base) + 32768 +                       \
            (wn*64 + (nh)*32 + ni*16 + fr)*128 + ((kk*64 + kby) ^ swz));      \
} while (0)

#define MQ(mh, nh, B) do {                                                    \
    _Pragma("unroll") for (int kk = 0; kk < 2; ++kk)                          \
    _Pragma("unroll") for (int mi = 0; mi < 4; ++mi)                          \
    _Pragma("unroll") for (int ni = 0; ni < 2; ++ni)                          \
        acc[(mh)*4+mi][(nh)*2+ni] = __builtin_amdgcn_mfma_f32_16x16x32_bf16(  \
            af[mi][kk], B[ni][kk], acc[(mh)*4+mi][(nh)*2+ni], 0, 0, 0);       \
} while (0)

#define PHASE_MFMA(mh, nh, B)                                                 \
    __builtin_amdgcn_s_barrier();                                             \
    asm volatile("s_waitcnt lgkmcnt(0)" ::: "memory");                        \
    __builtin_amdgcn_s_setprio(1);                                            \
    MQ(mh, nh, B);                                                            \
    __builtin_amdgcn_s_setprio(0);                                            \
    __builtin_amdgcn_s_barrier();

    const char* base0 = smem;            // even K-tiles
    const char* base1 = smem + 65536;    // odd K-tiles

    // ---- prologue: tile0 (all 4 pairs) + tile1 pair0; drain tile0, keep pair in flight ----
    // pair order per tile: p0={SA0,SA2} p1={SB0,SB1} p2={SB2,SB3} p3={SA1,SA3}
    SA(0,0,0); SA(0,2,0); SB(0,0,0); SB(0,1,0); SB(0,2,0); SB(0,3,0); SA(0,1,0); SA(0,3,0);
    SA(1,0,64); SA(1,2,64);                       // tile1: ij=0, ck=64
    asm volatile("s_waitcnt vmcnt(2)" ::: "memory");
    __builtin_amdgcn_s_barrier();

#pragma unroll 1
    for (int i = 0; i < 9; ++i) {
        // tile indices: t0=2i (buf0, P0-P3), t1=2i+1 (buf1, P4-P7)
        // staged here: t1 pairs1-3 (P0-P2), t2=2i+2 (P3-P6, buf0), t3=2i+3 pair0 (P7, buf1)
        const int iiA = i / 3,       jjA = i - 3 * iiA;          // ij of t1 = i
        const int iiB = (i + 1) / 3, jjB = (i + 1) - 3 * iiB;    // ij of t2,t3 = i+1
        const int offA1 = (iiA * WP + jjA) * CIN + 64;
        const int offB1 = i * (OCH * CIN) + 64;
        const int offA2 = (iiB * WP + jjB) * CIN;
        const int offB2 = (i + 1) * (OCH * CIN);
        const int offA3 = offA2 + 64;
        const bool pf = (i < 8);

        // P0: stage t1.p1 {SB0,SB1}; read A0,B0 of buf0; MFMA Q(0,0)
        SB(1,0,offB1); SB(1,1,offB1);
        READ_A(base0, 0);
        READ_B(base0, 0, bq0);
        PHASE_MFMA(0, 0, bq0);

        // P1: stage t1.p2 {SB2,SB3}; read B1; MFMA Q(0,1); wait: drain t0.p3
        SB(1,2,offB1); SB(1,3,offB1);
        READ_B(base0, 1, bq1);
        PHASE_MFMA(0, 1, bq1);
        asm volatile("s_waitcnt vmcnt(6)" ::: "memory");

        // P2: stage t1.p3 {SA1,SA3}; read A1; MFMA Q(1,1)
        SA(1,1,offA1); SA(1,3,offA1);
        READ_A(base0, 1);
        PHASE_MFMA(1, 1, bq1);

        // P3: stage t2.p0 {SA0,SA2}; MFMA Q(1,0); wait: drain t1.p0-p2; sync
        if (pf) { SA(0,0,offA2); SA(0,2,offA2); }
        __builtin_amdgcn_s_setprio(1);
        MQ(1, 0, bq0);
        __builtin_amdgcn_s_setprio(0);
        if (pf) asm volatile("s_waitcnt vmcnt(4)" ::: "memory");
        else    asm volatile("s_waitcnt vmcnt(2)" ::: "memory");
        __builtin_amdgcn_s_barrier();

        // P4: stage t2.p1; read A0,B0 of buf1; MFMA Q(0,0)
        if (pf) { SB(0,0,offB2); SB(0,1,offB2); }
        READ_A(base1, 0);
        READ_B(base1, 0, bq0);
        PHASE_MFMA(0, 0, bq0);

        // P5: stage t2.p2; read B1; MFMA Q(0,1); wait: drain t1.p3
        if (pf) { SB(0,2,offB2); SB(0,3,offB2); }
        READ_B(base1, 1, bq1);
        PHASE_MFMA(0, 1, bq1);
        if (pf) asm volatile("s_waitcnt vmcnt(6)" ::: "memory");
        else    asm volatile("s_waitcnt vmcnt(0)" ::: "memory");

        // P6: stage t2.p3; read A1; MFMA Q(1,1)
        if (pf) { SA(0,1,offA2); SA(0,3,offA2); }
        READ_A(base1, 1);
        PHASE_MFMA(1, 1, bq1);

        // P7: stage t3.p0; MFMA Q(1,0); wait: drain t2.p0-p2; sync
        if (pf) { SA(1,0,offA3); SA(1,2,offA3); }
        __builtin_amdgcn_s_setprio(1);
        MQ(1, 0, bq0);
        __builtin_amdgcn_s_setprio(0);
        if (pf) {
            asm volatile("s_waitcnt vmcnt(4)" ::: "memory");
            __builtin_amdgcn_s_barrier();
        }
    }
#undef SA
#undef SB
#undef READ_A
#undef READ_B
#undef MQ
#undef PHASE_MFMA

    // ---- epilogue: C/D map col=ln&15 (n), row=(ln>>4)*4+reg (pixel) ----
    const int laneR4 = (ln >> 4) * 4;
    float bn[4];
#pragma unroll
    for (int ni = 0; ni < 4; ++ni)
        bn[ni] = bias[wn * 64 + ni * 16 + fr];

#pragma unroll
    for (int mi = 0; mi < 8; ++mi) {
        int p0 = m0 + wm * 128 + mi * 16 + laneR4;
        int b  = p0 / HWSZ;
        int hw = p0 - b * HWSZ;
#pragma unroll
        for (int ni = 0; ni < 4; ++ni) {
            int n = wn * 64 + ni * 16 + fr;
            float4 v;
            v.x = acc[mi][ni][0] + bn[ni];
            v.y = acc[mi][ni][1] + bn[ni];
            v.z = acc[mi][ni][2] + bn[ni];
            v.w = acc[mi][ni][3] + bn[ni];
            *(float4*)(out + ((size_t)(b * OCH + n) * HWSZ + hw)) = v;
        }
    }
}

extern "C" void kernel_launch(void* const* d_in, const int* in_sizes, int n_in,
                              void* d_out, int out_size, void* d_ws, size_t ws_size,
                              hipStream_t stream) {
    const float* x    = (const float*)d_in[0];
    const float* w    = (const float*)d_in[1];
    const float* bias = (const float*)d_in[2];
    float* out = (float*)d_out;

    char* ws = (char*)d_ws;
    __hip_bfloat16* xbuf = (__hip_bfloat16*)ws;                   // 27,557,888 B
    __hip_bfloat16* wbuf = (__hip_bfloat16*)(ws + 27557888);      //    589,824 B

    hipFuncSetAttribute(reinterpret_cast<const void*>(conv_gemm),
                        hipFuncAttributeMaxDynamicSharedMemorySize, 131072);

    zero_border<<<456, 256, 0, stream>>>(xbuf);
    cast_transpose_x<<<dim3(98, 4, 32), dim3(32, 8), 0, stream>>>(x, xbuf);
    prep_w<<<9 * 256 * 128 / 256, 256, 0, stream>>>(w, wbuf);
    conv_gemm<<<392, 512, 131072, stream>>>(xbuf, wbuf, bias, out);
}

// Round 4
// 100.495 us; speedup vs baseline: 1.1070x; 1.0362x over previous
//
#include <hip/hip_runtime.h>
#include <hip/hip_bf16.h>
#include <cstdint>

typedef float f32x4 __attribute__((ext_vector_type(4)));
typedef short bf16x8 __attribute__((ext_vector_type(8)));
typedef short short8 __attribute__((ext_vector_type(8)));

#define CIN   128
#define WIMG  56
#define HWSZ  3136      // 56*56
#define OCH   256
#define HP    58
#define WP    58

// ---- prep A: border-zero (456 blocks) + weight repack (1152 blocks), merged ----
__global__ void small_prep(const float* __restrict__ wsrc,
                           __hip_bfloat16* __restrict__ wb,
                           __hip_bfloat16* __restrict__ xb) {
    int bidx = blockIdx.x;
    if (bidx < 456) {
        int idx = bidx * 256 + threadIdx.x;   // 116736 = 32*228*16
        int c8  = idx & 15;
        int t   = idx >> 4;
        int b   = t / 228;
        int pos = t - b * 228;
        int h, w;
        if (pos < 58)       { h = 0;             w = pos; }
        else if (pos < 116) { h = 57;            w = pos - 58; }
        else if (pos < 172) { h = pos - 116 + 1; w = 0; }
        else                { h = pos - 172 + 1; w = 57; }
        uint4 z = {0, 0, 0, 0};
        *(uint4*)((char*)xb + (((size_t)(b * HP + h) * WP + w) * CIN + c8 * 8) * 2) = z;
    } else {
        int idx = (bidx - 456) * 256 + threadIdx.x;   // 294912 = 9*256*128
        int c    = idx & 127;
        int rest = idx >> 7;
        int o    = rest & 255;
        int ij   = rest >> 8;
        wb[idx] = __float2bfloat16(wsrc[((size_t)o * CIN + c) * 9 + ij]);
    }
}

// ---- prep B: x [B][C][H][W] f32 -> xb padded NHWC bf16 [B][58][58][128], 16B stores ----
__global__ __launch_bounds__(256)
void cast_transpose_x(const float* __restrict__ x,
                      __hip_bfloat16* __restrict__ xb) {
    __shared__ float tile[64][33];
    const int hw0 = blockIdx.x * 32;
    const int c0  = blockIdx.y * 64;
    const int b   = blockIdx.z;

    // load: lanes sweep hw (coalesced), 8 c-rows per thread
    const int lx = threadIdx.x & 31;
    const int lc = threadIdx.x >> 5;   // 0..7
    const float* src = x + ((size_t)(b * CIN + c0 + lc) * HWSZ) + hw0 + lx;
#pragma unroll
    for (int k = 0; k < 8; ++k)
        tile[lc + k * 8][lx] = src[(size_t)(k * 8) * HWSZ];
    __syncthreads();

    // store: 8 lanes cover 64 c (contiguous 128B per hw)
    const int slot = threadIdx.x & 7;        // c-group of 8
    const int hwl  = threadIdx.x >> 3;       // 0..31
    int hw = hw0 + hwl;
    int h = hw / WIMG;
    int w = hw - h * WIMG;
    short8 v;
#pragma unroll
    for (int j = 0; j < 8; ++j) {
        __hip_bfloat16 hb = __float2bfloat16(tile[slot * 8 + j][hwl]);
        v[j] = *reinterpret_cast<short*>(&hb);
    }
    *(short8*)(xb + (((size_t)b * HP + (h + 1)) * WP + (w + 1)) * CIN + c0 + slot * 8) = v;
}

// ---- async global->LDS 16B ----
__device__ __forceinline__ void gload16(const void* g, void* l) {
    __builtin_amdgcn_global_load_lds(
        (const __attribute__((address_space(1))) unsigned*)g,
        (__attribute__((address_space(3))) unsigned*)l,
        16, 0, 0);
}

// ---- main: 256x256 tile, BK=64, 8 waves (2Mx4N), pinned 8-phase, 2 K-tiles/iter ----
__global__ __launch_bounds__(512, 2)
void conv_gemm(const __hip_bfloat16* __restrict__ xb,
               const __hip_bfloat16* __restrict__ wb,
               const float* __restrict__ bias,
               float* __restrict__ out) {
    extern __shared__ __attribute__((aligned(16))) char smem[];  // 131072

    const int tid = threadIdx.x;
    const int wv  = tid >> 6;
    const int ln  = tid & 63;

    int bid = blockIdx.x;
    bid = (bid & 7) * 49 + (bid >> 3);        // XCD swizzle: 392 = 8*49, bijective
    const int m0 = bid * 256;

    // ---- staging addresses (pre-swizzled source, linear LDS dest) ----
    const int srow = tid >> 3;
    const int cs   = tid & 7;
    const int colsrc = ((cs * 16) ^ ((srow & 7) << 4)) >> 1;
    int aOff[4], bOff[4];
#pragma unroll
    for (int q = 0; q < 4; ++q) {
        int row = q * 64 + srow;
        int p  = m0 + row;
        int b  = p / HWSZ;
        int hw = p - b * HWSZ;
        int h  = hw / WIMG;
        int w  = hw - h * WIMG;
        aOff[q] = ((b * HP + h) * WP + w) * CIN + colsrc;
        bOff[q] = row * CIN + colsrc;
    }
    const int ldsd = tid * 16;

#define SA(buf,q,offA_) gload16(xb + aOff[q] + (offA_), smem + (buf)*65536 + (q)*8192 + ldsd)
#define SB(buf,q,offB_) gload16(wb + bOff[q] + (offB_), smem + (buf)*65536 + 32768 + (q)*8192 + ldsd)

    // ---- compute-side constants ----
    const int wm  = wv >> 2;
    const int wn  = wv & 3;
    const int fr  = ln & 15;
    const int kby = (ln >> 4) * 16;
    const int swz = (ln & 7) << 4;

    f32x4 acc[8][4] = {};
    bf16x8 af[4][2], bq0[2][2], bq1[2][2];

#define READ_A(base, mh) do {                                                 \
    _Pragma("unroll") for (int mi = 0; mi < 4; ++mi)                          \
    _Pragma("unroll") for (int kk = 0; kk < 2; ++kk)                          \
        af[mi][kk] = *(const bf16x8*)((base) +                                \
            (wm*128 + (mh)*64 + mi*16 + fr)*128 + ((kk*64 + kby) ^ swz));     \
} while (0)

#define READ_B(base, nh, dst) do {                                            \
    _Pragma("unroll") for (int ni = 0; ni < 2; ++ni)                          \
    _Pragma("unroll") for (int kk = 0; kk < 2; ++kk)                          \
        dst[ni][kk] = *(const bf16x8*)((base) + 32768 +                       \
            (wn*64 + (nh)*32 + ni*16 + fr)*128 + ((kk*64 + kby) ^ swz));      \
} while (0)

#define MQ(mh, nh, B) do {                                                    \
    _Pragma("unroll") for (int kk = 0; kk < 2; ++kk)                          \
    _Pragma("unroll") for (int mi = 0; mi < 4; ++mi)                          \
    _Pragma("unroll") for (int ni = 0; ni < 2; ++ni)                          \
        acc[(mh)*4+mi][(nh)*2+ni] = __builtin_amdgcn_mfma_f32_16x16x32_bf16(  \
            af[mi][kk], B[ni][kk], acc[(mh)*4+mi][(nh)*2+ni], 0, 0, 0);       \
} while (0)

// pinned phase: open barrier, drain own ds_reads, fence, MFMA cluster, fence,
// optional counted vmcnt (BEFORE close barrier -> cross-wave safe), close barrier
#define VMW(N) do {                                                           \
    asm volatile("s_waitcnt vmcnt(" #N ")" ::: "memory");                     \
    __builtin_amdgcn_sched_barrier(0);                                        \
} while (0)

#define PHASE(MQCALL) do {                                                    \
    __builtin_amdgcn_s_barrier();                                             \
    asm volatile("s_waitcnt lgkmcnt(0)" ::: "memory");                        \
    __builtin_amdgcn_sched_barrier(0);                                        \
    __builtin_amdgcn_s_setprio(1);                                            \
    MQCALL;                                                                   \
    __builtin_amdgcn_s_setprio(0);                                            \
    __builtin_amdgcn_sched_barrier(0);                                        \
} while (0)

    const char* base0 = smem;
    const char* base1 = smem + 65536;

    // ---- prologue: t0 pairs p0..p3, then t1.p0; keep t1.p0 in flight ----
    SA(0,0,0); SA(0,2,0); SB(0,0,0); SB(0,1,0); SB(0,2,0); SB(0,3,0); SA(0,1,0); SA(0,3,0);
    SA(1,0,64); SA(1,2,64);
    asm volatile("s_waitcnt vmcnt(2)" ::: "memory");
    __builtin_amdgcn_s_barrier();

#pragma unroll 1
    for (int i = 0; i < 9; ++i) {
        const int iiA = i / 3,       jjA = i - 3 * iiA;          // tap of t1 = 2i+1
        const int iiB = (i + 1) / 3, jjB = (i + 1) - 3 * iiB;    // tap of t2,t3
        const int offA1 = (iiA * WP + jjA) * CIN + 64;
        const int offB1 = i * (OCH * CIN) + 64;
        const int offA2 = (iiB * WP + jjB) * CIN;
        const int offB2 = (i + 1) * (OCH * CIN);
        const int offA3 = offA2 + 64;
        const bool pf = (i < 8);

        // P0: reads buf0 A0,B0; stage t1.p1
        READ_A(base0, 0);
        READ_B(base0, 0, bq0);
        SB(1,0,offB1); SB(1,1,offB1);
        PHASE(MQ(0, 0, bq0));
        __builtin_amdgcn_s_barrier();

        // P1: reads buf0 B1; stage t1.p2; wait keeps {t1.p3-,t2-} none yet
        READ_B(base0, 1, bq1);
        SB(1,2,offB1); SB(1,3,offB1);
        PHASE(MQ(0, 1, bq1));
        VMW(6);                                  // lands t0.p3 (prev iter P6)
        __builtin_amdgcn_s_barrier();

        // P2: reads buf0 A1 (t0.p3); stage t1.p3
        READ_A(base0, 1);
        SA(1,1,offA1); SA(1,3,offA1);
        PHASE(MQ(1, 1, bq1));
        __builtin_amdgcn_s_barrier();

        // P3: no reads; stage t2.p0; drain to t1.p0-p2 landed
        if (pf) { SA(0,0,offA2); SA(0,2,offA2); }
        PHASE(MQ(1, 0, bq0));
        if (pf) VMW(4); else VMW(2);
        __builtin_amdgcn_s_barrier();

        // P4: reads buf1 A0,B0 (t1.p0,p1,p2); stage t2.p1
        READ_A(base1, 0);
        READ_B(base1, 0, bq0);
        if (pf) { SB(0,0,offB2); SB(0,1,offB2); }
        PHASE(MQ(0, 0, bq0));
        __builtin_amdgcn_s_barrier();

        // P5: reads buf1 B1; stage t2.p2; drain to t1.p3 landed
        READ_B(base1, 1, bq1);
        if (pf) { SB(0,2,offB2); SB(0,3,offB2); }
        PHASE(MQ(0, 1, bq1));
        if (pf) VMW(6); else VMW(0);
        __builtin_amdgcn_s_barrier();

        // P6: reads buf1 A1 (t1.p3); stage t2.p3
        READ_A(base1, 1);
        if (pf) { SA(0,1,offA2); SA(0,3,offA2); }
        PHASE(MQ(1, 1, bq1));
        __builtin_amdgcn_s_barrier();

        // P7: no reads; stage t3.p0; drain to t2.p0-p2 landed
        if (pf) { SA(1,0,offA3); SA(1,2,offA3); }
        PHASE(MQ(1, 0, bq0));
        if (pf) {
            VMW(4);
            __builtin_amdgcn_s_barrier();
        }
    }
#undef SA
#undef SB
#undef READ_A
#undef READ_B
#undef MQ
#undef PHASE
#undef VMW

    // ---- epilogue: C/D map col=ln&15 (n), row=(ln>>4)*4+reg (pixel) ----
    const int laneR4 = (ln >> 4) * 4;
    float bn[4];
#pragma unroll
    for (int ni = 0; ni < 4; ++ni)
        bn[ni] = bias[wn * 64 + ni * 16 + fr];

#pragma unroll
    for (int mi = 0; mi < 8; ++mi) {
        int p0 = m0 + wm * 128 + mi * 16 + laneR4;
        int b  = p0 / HWSZ;
        int hw = p0 - b * HWSZ;
#pragma unroll
        for (int ni = 0; ni < 4; ++ni) {
            int n = wn * 64 + ni * 16 + fr;
            float4 v;
            v.x = acc[mi][ni][0] + bn[ni];
            v.y = acc[mi][ni][1] + bn[ni];
            v.z = acc[mi][ni][2] + bn[ni];
            v.w = acc[mi][ni][3] + bn[ni];
            *(float4*)(out + ((size_t)(b * OCH + n) * HWSZ + hw)) = v;
        }
    }
}

extern "C" void kernel_launch(void* const* d_in, const int* in_sizes, int n_in,
                              void* d_out, int out_size, void* d_ws, size_t ws_size,
                              hipStream_t stream) {
    const float* x    = (const float*)d_in[0];
    const float* w    = (const float*)d_in[1];
    const float* bias = (const float*)d_in[2];
    float* out = (float*)d_out;

    char* ws = (char*)d_ws;
    __hip_bfloat16* xbuf = (__hip_bfloat16*)ws;                   // 27,557,888 B
    __hip_bfloat16* wbuf = (__hip_bfloat16*)(ws + 27557888);      //    589,824 B

    hipFuncSetAttribute(reinterpret_cast<const void*>(conv_gemm),
                        hipFuncAttributeMaxDynamicSharedMemorySize, 131072);

    small_prep<<<1608, 256, 0, stream>>>(w, wbuf, xbuf);
    cast_transpose_x<<<dim3(98, 2, 32), dim3(256), 0, stream>>>(x, xbuf);
    conv_gemm<<<392, 512, 131072, stream>>>(xbuf, wbuf, bias, out);
}